// Round 5
// baseline (445.157 us; speedup 1.0000x reference)
//
#include <hip/hip_runtime.h>
#include <math.h>

#define B   32
#define T   2048
#define H   1024
#define OUTD 256
#define NC  32     // t-chunks in fused kernel (chunk = 64 rows)
#define KC1 16     // k-chunks in k1a (chunk = 64)

// ---------------- k1a: partial h_t = hs[:, T-1, :] @ W1 (k-split partials) ----
__global__ __launch_bounds__(256) void k1a_partial_ht(
    const float* __restrict__ hs, const float* __restrict__ W1,
    float* __restrict__ ph)
{
    const int tid = threadIdx.x;
    const int h   = blockIdx.x * 256 + tid;   // 4 h-tiles
    const int k0  = blockIdx.y * 64;          // 16 k-chunks

    __shared__ float s_hs[B][64];
    for (int it = 0; it < 8; ++it) {
        int idx = tid + it * 256;
        int b = idx >> 6, k = idx & 63;
        s_hs[b][k] = hs[((size_t)(b * T + (T - 1)) << 10) + k0 + k];
    }
    __syncthreads();

    float acc[B];
#pragma unroll
    for (int b = 0; b < B; ++b) acc[b] = 0.f;

    for (int k4 = 0; k4 < 16; ++k4) {
        float w0 = W1[(size_t)(k0 + k4 * 4 + 0) * H + h];
        float w1 = W1[(size_t)(k0 + k4 * 4 + 1) * H + h];
        float w2 = W1[(size_t)(k0 + k4 * 4 + 2) * H + h];
        float w3 = W1[(size_t)(k0 + k4 * 4 + 3) * H + h];
#pragma unroll
        for (int b = 0; b < B; ++b) {
            const float4 hv = *(const float4*)&s_hs[b][k4 * 4];
            acc[b] = fmaf(hv.x, w0, acc[b]);
            acc[b] = fmaf(hv.y, w1, acc[b]);
            acc[b] = fmaf(hv.z, w2, acc[b]);
            acc[b] = fmaf(hv.w, w3, acc[b]);
        }
    }
    float* dst = ph + ((size_t)blockIdx.y * B << 10);
#pragma unroll
    for (int b = 0; b < B; ++b) dst[((size_t)b << 10) + h] = acc[b];
}

// ---------------- k1b: h_t = sum(partials) + b1 ------------------------------
__global__ __launch_bounds__(256) void k1b_reduce_ht(
    const float* __restrict__ ph, const float* __restrict__ b1,
    float* __restrict__ h_t)
{
    int i = blockIdx.x * 256 + threadIdx.x;   // 0..B*H-1 (i = b*H + h)
    int h = i & (H - 1);
    float s = b1[h];
#pragma unroll
    for (int c = 0; c < KC1; ++c)
        s += ph[((size_t)c * B << 10) + i];
    h_t[i] = s;
}

// ---------------- k2: u[b,k] = dot(W1[k,:], h_t[b,:]) — batched butterfly ----
// All 32 b-dots accumulated first, then ONE 6-step butterfly over 32
// independent values per step: 192 independent shuffles (throughput-bound)
// instead of 32 dependent 6-chains (latency-bound).
__global__ __launch_bounds__(256) void k2_compute_u(
    const float* __restrict__ W1, const float* __restrict__ h_t,
    float* __restrict__ u)
{
    const int wid  = threadIdx.x >> 6;
    const int lane = threadIdx.x & 63;
    const int k    = blockIdx.x * 4 + wid;    // 256 blocks x 4 waves = 1024 k
    const float4* wr = (const float4*)(W1 + ((size_t)k << 10));
    float4 wq[4];
#pragma unroll
    for (int j = 0; j < 4; ++j) wq[j] = wr[lane + 64 * j];

    float s[B];
#pragma unroll 8
    for (int b = 0; b < B; ++b) {
        const float4* hr = (const float4*)(h_t + ((size_t)b << 10));
        float t = 0.f;
#pragma unroll
        for (int j = 0; j < 4; ++j) {
            float4 hv = hr[lane + 64 * j];
            t += wq[j].x * hv.x + wq[j].y * hv.y + wq[j].z * hv.z + wq[j].w * hv.w;
        }
        s[b] = t;
    }
#pragma unroll
    for (int off = 32; off; off >>= 1) {
#pragma unroll
        for (int b = 0; b < B; ++b) s[b] += __shfl_xor(s[b], off, 64);
    }
    if (lane == 0) {
#pragma unroll
        for (int b = 0; b < B; ++b) u[((size_t)b << 10) + k] = s[b];
    }
}

// ---------------- k3: fused score + online softmax + weighted pooling --------
// Two-row lookahead: prefetch row r+2 while computing row r, so the per-row
// vmcnt wait has ~2 rows of compute to hide HBM latency under.
__global__ __launch_bounds__(256) void k3_fused(
    const float* __restrict__ hs, const float* __restrict__ u,
    float* __restrict__ ctx_p, float* __restrict__ m_p, float* __restrict__ l_p)
{
    const int c    = blockIdx.x;          // t-chunk (0..31)
    const int b    = blockIdx.y;          // batch
    const int w    = threadIdx.x >> 6;    // wave 0..3
    const int lane = threadIdx.x & 63;
    const int tid  = threadIdx.x;

    const float4* urow = (const float4*)(u + ((size_t)b << 10));
    float4 uq[4];
#pragma unroll
    for (int j = 0; j < 4; ++j) uq[j] = urow[lane + 64 * j];

    const int t0 = c * 64 + w * 16;       // 16 rows per wave
    const float4* base = (const float4*)(hs + ((size_t)(b * T + t0) << 10));

    float m = -INFINITY, lsum = 0.f;
    float4 acc[4];
#pragma unroll
    for (int j = 0; j < 4; ++j) acc[j] = make_float4(0.f, 0.f, 0.f, 0.f);

    float4 x[4], y[4], z[4];
#pragma unroll
    for (int j = 0; j < 4; ++j) x[j] = base[lane + 64 * j];
#pragma unroll
    for (int j = 0; j < 4; ++j) y[j] = base[256 + lane + 64 * j];

    for (int r = 0; r < 16; ++r) {
        if (r < 14) {
#pragma unroll
            for (int j = 0; j < 4; ++j) z[j] = base[(r + 2) * 256 + lane + 64 * j];
        }
        float s = 0.f;
#pragma unroll
        for (int j = 0; j < 4; ++j)
            s += x[j].x * uq[j].x + x[j].y * uq[j].y + x[j].z * uq[j].z + x[j].w * uq[j].w;
#pragma unroll
        for (int off = 32; off; off >>= 1) s += __shfl_xor(s, off, 64);

        float mn = fmaxf(m, s);
        float al = __expf(m - mn);     // exp(-inf)=0 on first row
        float wt = __expf(s - mn);
        lsum = lsum * al + wt;
#pragma unroll
        for (int j = 0; j < 4; ++j) {
            acc[j].x = fmaf(acc[j].x, al, wt * x[j].x);
            acc[j].y = fmaf(acc[j].y, al, wt * x[j].y);
            acc[j].z = fmaf(acc[j].z, al, wt * x[j].z);
            acc[j].w = fmaf(acc[j].w, al, wt * x[j].w);
        }
        m = mn;
#pragma unroll
        for (int j = 0; j < 4; ++j) { x[j] = y[j]; y[j] = z[j]; }
    }

    // ---- combine 4 waves within block ----
    __shared__ float sm[4], sl[4];
    __shared__ float sacc[4][H];          // 16 KB
    if (lane == 0) { sm[w] = m; sl[w] = lsum; }
    __syncthreads();
    const float mp = fmaxf(fmaxf(sm[0], sm[1]), fmaxf(sm[2], sm[3]));
    const float alw = __expf(m - mp);
    float4* sa = (float4*)&sacc[w][0];
#pragma unroll
    for (int j = 0; j < 4; ++j) {
        float4 v;
        v.x = acc[j].x * alw; v.y = acc[j].y * alw;
        v.z = acc[j].z * alw; v.w = acc[j].w * alw;
        sa[lane + 64 * j] = v;
    }
    __syncthreads();
    float lp = 0.f;
#pragma unroll
    for (int ww = 0; ww < 4; ++ww) lp += sl[ww] * __expf(sm[ww] - mp);

    float* dst = ctx_p + (((size_t)b * NC + c) << 10);
#pragma unroll
    for (int i = 0; i < 4; ++i) {
        int h = tid + 256 * i;
        dst[h] = sacc[0][h] + sacc[1][h] + sacc[2][h] + sacc[3][h];
    }
    if (tid == 0) { m_p[b * NC + c] = mp; l_p[b * NC + c] = lp; }
}

// ---------------- k46: combine + pre(LDS) + pre@Wv + tanh, one block per b ---
// 1024 threads: o = tid&255, q = tid>>8 (k-quarter of 512). pre[2048] built in
// LDS (ctx combine for k<1024, h_t copy for k>=1024); each quarter runs 512
// fma iterations against Wv; LDS tree-combine; fused bias+tanh store.
__global__ __launch_bounds__(1024) void k46_out(
    const float* __restrict__ ctx_p, const float* __restrict__ m_p,
    const float* __restrict__ l_p, const float* __restrict__ h_t,
    const float* __restrict__ Wv, const float* __restrict__ bv,
    float* __restrict__ out)
{
    const int b   = blockIdx.x;
    const int tid = threadIdx.x;
    const int o   = tid & 255;
    const int q   = tid >> 8;

    __shared__ float sp[2 * H];        // 8 KB
    __shared__ float red[4][OUTD];     // 4 KB

    // softmax-combine factors (redundant per thread; m_p/l_p are 128 B, L2)
    float M = -INFINITY;
#pragma unroll
    for (int c = 0; c < NC; ++c) M = fmaxf(M, m_p[b * NC + c]);
    float L = 0.f;
#pragma unroll
    for (int c = 0; c < NC; ++c) L += l_p[b * NC + c] * __expf(m_p[b * NC + c] - M);

    // pre[tid] = combined context for h = tid
    float s = 0.f;
#pragma unroll
    for (int c = 0; c < NC; ++c)
        s += ctx_p[(((size_t)b * NC + c) << 10) + tid] * __expf(m_p[b * NC + c] - M);
    sp[tid] = s / L;
    // pre[1024 + tid] = h_t
    sp[H + tid] = h_t[((size_t)b << 10) + tid];
    __syncthreads();

    float acc = 0.f;
    const float* wv = Wv + ((size_t)q * 512) * OUTD + o;
    const float* pq = sp + q * 512;
#pragma unroll 8
    for (int k = 0; k < 512; ++k)
        acc = fmaf(pq[k], wv[(size_t)k * OUTD], acc);
    red[q][o] = acc;
    __syncthreads();

    if (tid < OUTD)
        out[b * OUTD + tid] = tanhf(red[0][tid] + red[1][tid] + red[2][tid]
                                    + red[3][tid] + bv[tid]);
}

extern "C" void kernel_launch(void* const* d_in, const int* in_sizes, int n_in,
                              void* d_out, int out_size, void* d_ws, size_t ws_size,
                              hipStream_t stream)
{
    const float* hs = (const float*)d_in[0];
    const float* W1 = (const float*)d_in[1];
    const float* b1 = (const float*)d_in[2];
    const float* Wv = (const float*)d_in[3];
    const float* bv = (const float*)d_in[4];
    float* out = (float*)d_out;
    float* ws  = (float*)d_ws;

    float* ph    = ws;                              // KC1*B*H  = 524288 floats
    float* h_t   = ph + (size_t)KC1 * B * H;        // B*H      = 32768
    float* u     = h_t + (size_t)B * H;             // B*H      = 32768
    float* m_p   = u + (size_t)B * H;               // B*NC     = 1024
    float* l_p   = m_p + B * NC;                    // B*NC     = 1024
    float* ctx_p = l_p + B * NC;                    // B*NC*H   = 1048576
    // total ~6.5 MB of d_ws

    k1a_partial_ht<<<dim3(4, KC1), 256, 0, stream>>>(hs, W1, ph);
    k1b_reduce_ht<<<(B * H) / 256, 256, 0, stream>>>(ph, b1, h_t);
    k2_compute_u<<<H / 4, 256, 0, stream>>>(W1, h_t, u);
    k3_fused<<<dim3(NC, B), 256, 0, stream>>>(hs, u, ctx_p, m_p, l_p);
    k46_out<<<B, 1024, 0, stream>>>(ctx_p, m_p, l_p, h_t, Wv, bv, out);
}

// Round 6
// 436.606 us; speedup vs baseline: 1.0196x; 1.0196x over previous
//
#include <hip/hip_runtime.h>
#include <math.h>

#define B   32
#define T   2048
#define H   1024
#define OUTD 256
#define NC  32     // t-chunks in fused kernel (chunk = 64 rows)
#define KC1 16     // k-chunks in k1a (chunk = 64)

// ---------------- k1a: partial h_t = hs[:, T-1, :] @ W1 (k-split partials) ----
__global__ __launch_bounds__(256) void k1a_partial_ht(
    const float* __restrict__ hs, const float* __restrict__ W1,
    float* __restrict__ ph)
{
    const int tid = threadIdx.x;
    const int h   = blockIdx.x * 256 + tid;   // 4 h-tiles
    const int k0  = blockIdx.y * 64;          // 16 k-chunks

    __shared__ float s_hs[B][64];
    for (int it = 0; it < 8; ++it) {
        int idx = tid + it * 256;
        int b = idx >> 6, k = idx & 63;
        s_hs[b][k] = hs[((size_t)(b * T + (T - 1)) << 10) + k0 + k];
    }
    __syncthreads();

    float acc[B];
#pragma unroll
    for (int b = 0; b < B; ++b) acc[b] = 0.f;

    for (int k4 = 0; k4 < 16; ++k4) {
        float w0 = W1[(size_t)(k0 + k4 * 4 + 0) * H + h];
        float w1 = W1[(size_t)(k0 + k4 * 4 + 1) * H + h];
        float w2 = W1[(size_t)(k0 + k4 * 4 + 2) * H + h];
        float w3 = W1[(size_t)(k0 + k4 * 4 + 3) * H + h];
#pragma unroll
        for (int b = 0; b < B; ++b) {
            const float4 hv = *(const float4*)&s_hs[b][k4 * 4];
            acc[b] = fmaf(hv.x, w0, acc[b]);
            acc[b] = fmaf(hv.y, w1, acc[b]);
            acc[b] = fmaf(hv.z, w2, acc[b]);
            acc[b] = fmaf(hv.w, w3, acc[b]);
        }
    }
    float* dst = ph + ((size_t)blockIdx.y * B << 10);
#pragma unroll
    for (int b = 0; b < B; ++b) dst[((size_t)b << 10) + h] = acc[b];
}

// ---------------- k1b: h_t = sum(partials) + b1; also zero accum -------------
__global__ __launch_bounds__(256) void k1b_reduce_ht(
    const float* __restrict__ ph, const float* __restrict__ b1,
    float* __restrict__ h_t, float* __restrict__ accum)
{
    int i = blockIdx.x * 256 + threadIdx.x;   // 0..B*H-1 (i = b*H + h)
    int h = i & (H - 1);
    float s = b1[h];
#pragma unroll
    for (int c = 0; c < KC1; ++c)
        s += ph[((size_t)c * B << 10) + i];
    h_t[i] = s;
    if (i < B * OUTD) accum[i] = 0.f;         // replaces hipMemsetAsync
}

// ---------------- k2: u[b,k] = dot(W1[k,:], h_t[b,:]) — batched butterfly ----
__global__ __launch_bounds__(256) void k2_compute_u(
    const float* __restrict__ W1, const float* __restrict__ h_t,
    float* __restrict__ u)
{
    const int wid  = threadIdx.x >> 6;
    const int lane = threadIdx.x & 63;
    const int k    = blockIdx.x * 4 + wid;    // 256 blocks x 4 waves = 1024 k
    const float4* wr = (const float4*)(W1 + ((size_t)k << 10));
    float4 wq[4];
#pragma unroll
    for (int j = 0; j < 4; ++j) wq[j] = wr[lane + 64 * j];

    float s[B];
#pragma unroll 8
    for (int b = 0; b < B; ++b) {
        const float4* hr = (const float4*)(h_t + ((size_t)b << 10));
        float t = 0.f;
#pragma unroll
        for (int j = 0; j < 4; ++j) {
            float4 hv = hr[lane + 64 * j];
            t += wq[j].x * hv.x + wq[j].y * hv.y + wq[j].z * hv.z + wq[j].w * hv.w;
        }
        s[b] = t;
    }
#pragma unroll
    for (int off = 32; off; off >>= 1) {
#pragma unroll
        for (int b = 0; b < B; ++b) s[b] += __shfl_xor(s[b], off, 64);
    }
    if (lane == 0) {
#pragma unroll
        for (int b = 0; b < B; ++b) u[((size_t)b << 10) + k] = s[b];
    }
}

// ---------------- k3: fused score + online softmax + weighted pooling --------
// Rows processed in pairs: 2 independent dots, interleaved butterflies, one
// fused two-row online-softmax update (exact algebra, 3 exps per 2 rows).
// Ping-pong prefetch of the next 2-row group (8 KB/wave in flight).
__global__ __launch_bounds__(256) void k3_fused(
    const float* __restrict__ hs, const float* __restrict__ u,
    float* __restrict__ ctx_p, float* __restrict__ m_p, float* __restrict__ l_p)
{
    const int c    = blockIdx.x;          // t-chunk (0..31)
    const int b    = blockIdx.y;          // batch
    const int w    = threadIdx.x >> 6;    // wave 0..3
    const int lane = threadIdx.x & 63;
    const int tid  = threadIdx.x;

    const float4* urow = (const float4*)(u + ((size_t)b << 10));
    float4 uq[4];
#pragma unroll
    for (int j = 0; j < 4; ++j) uq[j] = urow[lane + 64 * j];

    const int t0 = c * 64 + w * 16;       // 16 rows per wave = 8 groups of 2
    const float4* base = (const float4*)(hs + ((size_t)(b * T + t0) << 10));

    float m = -INFINITY, lsum = 0.f;
    float4 acc[4];
#pragma unroll
    for (int j = 0; j < 4; ++j) acc[j] = make_float4(0.f, 0.f, 0.f, 0.f);

    float4 x[2][4], y[2][4];
#pragma unroll
    for (int j = 0; j < 4; ++j) {
        x[0][j] = base[      lane + 64 * j];   // row 0
        x[1][j] = base[256 + lane + 64 * j];   // row 1
        y[0][j] = base[512 + lane + 64 * j];   // row 2
        y[1][j] = base[768 + lane + 64 * j];   // row 3
    }

    for (int g = 0; g < 8; ++g) {
        // two independent dots
        float s0 = 0.f, s1 = 0.f;
#pragma unroll
        for (int j = 0; j < 4; ++j) {
            s0 += x[0][j].x * uq[j].x + x[0][j].y * uq[j].y
                + x[0][j].z * uq[j].z + x[0][j].w * uq[j].w;
            s1 += x[1][j].x * uq[j].x + x[1][j].y * uq[j].y
                + x[1][j].z * uq[j].z + x[1][j].w * uq[j].w;
        }
        // interleaved butterflies — the two chains hide each other's latency
#pragma unroll
        for (int off = 32; off; off >>= 1) {
            s0 += __shfl_xor(s0, off, 64);
            s1 += __shfl_xor(s1, off, 64);
        }
        // fused two-row online-softmax update (exact)
        float mn = fmaxf(m, fmaxf(s0, s1));
        float al = __expf(m - mn);            // exp(-inf)=0 on first group
        float w0 = __expf(s0 - mn);
        float w1 = __expf(s1 - mn);
        lsum = lsum * al + w0 + w1;
#pragma unroll
        for (int j = 0; j < 4; ++j) {
            acc[j].x = fmaf(acc[j].x, al, w0 * x[0][j].x + w1 * x[1][j].x);
            acc[j].y = fmaf(acc[j].y, al, w0 * x[0][j].y + w1 * x[1][j].y);
            acc[j].z = fmaf(acc[j].z, al, w0 * x[0][j].z + w1 * x[1][j].z);
            acc[j].w = fmaf(acc[j].w, al, w0 * x[0][j].w + w1 * x[1][j].w);
        }
        m = mn;
        // rotate buffers; prefetch group g+2 (rows 2g+4, 2g+5)
        if (g < 7) {
#pragma unroll
            for (int j = 0; j < 4; ++j) { x[0][j] = y[0][j]; x[1][j] = y[1][j]; }
        }
        if (g < 6) {
            const float4* nb = base + (size_t)(g + 2) * 512;
#pragma unroll
            for (int j = 0; j < 4; ++j) {
                y[0][j] = nb[      lane + 64 * j];
                y[1][j] = nb[256 + lane + 64 * j];
            }
        }
    }

    // ---- combine 4 waves within block ----
    __shared__ float sm[4], sl[4];
    __shared__ float sacc[4][H];          // 16 KB
    if (lane == 0) { sm[w] = m; sl[w] = lsum; }
    __syncthreads();
    const float mp = fmaxf(fmaxf(sm[0], sm[1]), fmaxf(sm[2], sm[3]));
    const float alw = __expf(m - mp);
    float4* sa = (float4*)&sacc[w][0];
#pragma unroll
    for (int j = 0; j < 4; ++j) {
        float4 v;
        v.x = acc[j].x * alw; v.y = acc[j].y * alw;
        v.z = acc[j].z * alw; v.w = acc[j].w * alw;
        sa[lane + 64 * j] = v;
    }
    __syncthreads();
    float lp = 0.f;
#pragma unroll
    for (int ww = 0; ww < 4; ++ww) lp += sl[ww] * __expf(sm[ww] - mp);

    float* dst = ctx_p + (((size_t)b * NC + c) << 10);
#pragma unroll
    for (int i = 0; i < 4; ++i) {
        int h = tid + 256 * i;
        dst[h] = sacc[0][h] + sacc[1][h] + sacc[2][h] + sacc[3][h];
    }
    if (tid == 0) { m_p[b * NC + c] = mp; l_p[b * NC + c] = lp; }
}

// ---------------- k45: fused chunk-combine + pre-slice + matmul + atomic -----
__global__ __launch_bounds__(256) void k45_matmul(
    const float* __restrict__ ctx_p, const float* __restrict__ m_p,
    const float* __restrict__ l_p, const float* __restrict__ h_t,
    const float* __restrict__ Wv, float* __restrict__ accum)
{
    const int kc = blockIdx.x;   // 0..7 (k-chunk of 256)
    const int b  = blockIdx.y;
    const int o  = threadIdx.x;

    __shared__ float sp[256];
    if (kc < 4) {
        float M = -INFINITY;
#pragma unroll
        for (int c = 0; c < NC; ++c) M = fmaxf(M, m_p[b * NC + c]);
        float L = 0.f;
#pragma unroll
        for (int c = 0; c < NC; ++c) L += l_p[b * NC + c] * __expf(m_p[b * NC + c] - M);
        float s = 0.f;
#pragma unroll
        for (int c = 0; c < NC; ++c)
            s += ctx_p[(((size_t)b * NC + c) << 10) + kc * 256 + o]
                 * __expf(m_p[b * NC + c] - M);
        sp[o] = s / L;
    } else {
        sp[o] = h_t[((size_t)b << 10) + (kc - 4) * 256 + o];
    }
    __syncthreads();

    float acc = 0.f;
    const float* wv = Wv + (size_t)kc * 256 * OUTD + o;
#pragma unroll 8
    for (int k = 0; k < 256; ++k)
        acc = fmaf(sp[k], wv[(size_t)k * OUTD], acc);
    atomicAdd(&accum[b * OUTD + o], acc);
}

// ---------------- k5b: out = tanh(accum + bv) --------------------------------
__global__ __launch_bounds__(256) void k5b_tanh(
    const float* __restrict__ accum, const float* __restrict__ bv,
    float* __restrict__ out)
{
    int i = blockIdx.x * 256 + threadIdx.x;
    out[i] = tanhf(accum[i] + bv[i & (OUTD - 1)]);
}

extern "C" void kernel_launch(void* const* d_in, const int* in_sizes, int n_in,
                              void* d_out, int out_size, void* d_ws, size_t ws_size,
                              hipStream_t stream)
{
    const float* hs = (const float*)d_in[0];
    const float* W1 = (const float*)d_in[1];
    const float* b1 = (const float*)d_in[2];
    const float* Wv = (const float*)d_in[3];
    const float* bv = (const float*)d_in[4];
    float* out = (float*)d_out;
    float* ws  = (float*)d_ws;

    float* ph    = ws;                              // KC1*B*H  = 524288 floats
    float* h_t   = ph + (size_t)KC1 * B * H;        // B*H      = 32768
    float* u     = h_t + (size_t)B * H;             // B*H      = 32768
    float* m_p   = u + (size_t)B * H;               // B*NC     = 1024
    float* l_p   = m_p + B * NC;                    // B*NC     = 1024
    float* ctx_p = l_p + B * NC;                    // B*NC*H   = 1048576
    float* accum = ctx_p + (size_t)B * NC * H;      // B*OUTD   = 8192
    // total ~6.6 MB of d_ws

    k1a_partial_ht<<<dim3(4, KC1), 256, 0, stream>>>(hs, W1, ph);
    k1b_reduce_ht<<<(B * H) / 256, 256, 0, stream>>>(ph, b1, h_t, accum);
    k2_compute_u<<<H / 4, 256, 0, stream>>>(W1, h_t, u);
    k3_fused<<<dim3(NC, B), 256, 0, stream>>>(hs, u, ctx_p, m_p, l_p);
    k45_matmul<<<dim3(8, B), 256, 0, stream>>>(ctx_p, m_p, l_p, h_t, Wv, accum);
    k5b_tanh<<<B, 256, 0, stream>>>(accum, bv, out);
}

// Round 8
// 417.521 us; speedup vs baseline: 1.0662x; 1.0457x over previous
//
#include <hip/hip_runtime.h>
#include <math.h>

#define B   32
#define T   2048
#define H   1024
#define OUTD 256
#define NC  32     // t-chunks in fused kernel (chunk = 64 rows)
#define KC1 32     // k-chunks in k1a (chunk = 32)

// ---------------- k1a: partial h_t = hs[:, T-1, :] @ W1 (k-split partials) ----
// 128 blocks (4 h-tiles x 32 k-chunks). All 32 W1 values per thread preloaded
// (one vmcnt wait for the whole block of loads), then a fully-unrolled FMA
// sweep — no per-iteration exposed HBM latency.
__global__ __launch_bounds__(256) void k1a_partial_ht(
    const float* __restrict__ hs, const float* __restrict__ W1,
    float* __restrict__ ph)
{
    const int tid = threadIdx.x;
    const int h   = blockIdx.x * 256 + tid;   // 4 h-tiles
    const int k0  = blockIdx.y * 32;          // 32 k-chunks

    __shared__ float s_hs[B][32];
    for (int it = 0; it < 4; ++it) {
        int idx = tid + it * 256;
        int b = idx >> 5, k = idx & 31;
        s_hs[b][k] = hs[((size_t)(b * T + (T - 1)) << 10) + k0 + k];
    }
    __syncthreads();

    float wv[32];
#pragma unroll
    for (int i = 0; i < 32; ++i)
        wv[i] = W1[(size_t)(k0 + i) * H + h];

    float acc[B];
#pragma unroll
    for (int b = 0; b < B; ++b) acc[b] = 0.f;

#pragma unroll
    for (int k4 = 0; k4 < 8; ++k4) {
#pragma unroll
        for (int b = 0; b < B; ++b) {
            const float4 hv = *(const float4*)&s_hs[b][k4 * 4];
            acc[b] = fmaf(hv.x, wv[k4 * 4 + 0], acc[b]);
            acc[b] = fmaf(hv.y, wv[k4 * 4 + 1], acc[b]);
            acc[b] = fmaf(hv.z, wv[k4 * 4 + 2], acc[b]);
            acc[b] = fmaf(hv.w, wv[k4 * 4 + 3], acc[b]);
        }
    }
    float* dst = ph + ((size_t)blockIdx.y * B << 10);
#pragma unroll
    for (int b = 0; b < B; ++b) dst[((size_t)b << 10) + h] = acc[b];
}

// ---------------- k1b: h_t = sum(partials) + b1; also zero accum -------------
__global__ __launch_bounds__(256) void k1b_reduce_ht(
    const float* __restrict__ ph, const float* __restrict__ b1,
    float* __restrict__ h_t, float* __restrict__ accum)
{
    int i = blockIdx.x * 256 + threadIdx.x;   // 0..B*H-1 (i = b*H + h)
    int h = i & (H - 1);
    float s = b1[h];
#pragma unroll
    for (int c = 0; c < KC1; ++c)
        s += ph[((size_t)c * B << 10) + i];
    h_t[i] = s;
    if (i < B * OUTD) accum[i] = 0.f;         // replaces hipMemsetAsync
}

// ---------------- k2: u[b,k] = dot(W1[k,:], h_t[b,:]) ------------------------
__global__ __launch_bounds__(256) void k2_compute_u(
    const float* __restrict__ W1, const float* __restrict__ h_t,
    float* __restrict__ u)
{
    const int wid  = threadIdx.x >> 6;
    const int lane = threadIdx.x & 63;
    const int k    = blockIdx.x * 4 + wid;    // 256 blocks x 4 waves = 1024 k
    const float4* wr = (const float4*)(W1 + ((size_t)k << 10));
    float4 wq[4];
#pragma unroll
    for (int j = 0; j < 4; ++j) wq[j] = wr[lane + 64 * j];

    for (int b = 0; b < B; ++b) {
        const float4* hr = (const float4*)(h_t + ((size_t)b << 10));
        float s = 0.f;
#pragma unroll
        for (int j = 0; j < 4; ++j) {
            float4 hv = hr[lane + 64 * j];
            s += wq[j].x * hv.x + wq[j].y * hv.y + wq[j].z * hv.z + wq[j].w * hv.w;
        }
#pragma unroll
        for (int off = 32; off; off >>= 1) s += __shfl_xor(s, off, 64);
        if (lane == 0) u[((size_t)b << 10) + k] = s;
    }
}

// ---------------- k3: fused score + online softmax + weighted pooling --------
// Two-row lookahead: prefetch row r+2 while computing row r.
__global__ __launch_bounds__(256) void k3_fused(
    const float* __restrict__ hs, const float* __restrict__ u,
    float* __restrict__ ctx_p, float* __restrict__ m_p, float* __restrict__ l_p)
{
    const int c    = blockIdx.x;          // t-chunk (0..31)
    const int b    = blockIdx.y;          // batch
    const int w    = threadIdx.x >> 6;    // wave 0..3
    const int lane = threadIdx.x & 63;
    const int tid  = threadIdx.x;

    const float4* urow = (const float4*)(u + ((size_t)b << 10));
    float4 uq[4];
#pragma unroll
    for (int j = 0; j < 4; ++j) uq[j] = urow[lane + 64 * j];

    const int t0 = c * 64 + w * 16;       // 16 rows per wave
    const float4* base = (const float4*)(hs + ((size_t)(b * T + t0) << 10));

    float m = -INFINITY, lsum = 0.f;
    float4 acc[4];
#pragma unroll
    for (int j = 0; j < 4; ++j) acc[j] = make_float4(0.f, 0.f, 0.f, 0.f);

    float4 x[4], y[4], z[4];
#pragma unroll
    for (int j = 0; j < 4; ++j) x[j] = base[lane + 64 * j];
#pragma unroll
    for (int j = 0; j < 4; ++j) y[j] = base[256 + lane + 64 * j];

    for (int r = 0; r < 16; ++r) {
        if (r < 14) {
#pragma unroll
            for (int j = 0; j < 4; ++j) z[j] = base[(r + 2) * 256 + lane + 64 * j];
        }
        float s = 0.f;
#pragma unroll
        for (int j = 0; j < 4; ++j)
            s += x[j].x * uq[j].x + x[j].y * uq[j].y + x[j].z * uq[j].z + x[j].w * uq[j].w;
#pragma unroll
        for (int off = 32; off; off >>= 1) s += __shfl_xor(s, off, 64);

        float mn = fmaxf(m, s);
        float al = __expf(m - mn);     // exp(-inf)=0 on first row
        float wt = __expf(s - mn);
        lsum = lsum * al + wt;
#pragma unroll
        for (int j = 0; j < 4; ++j) {
            acc[j].x = fmaf(acc[j].x, al, wt * x[j].x);
            acc[j].y = fmaf(acc[j].y, al, wt * x[j].y);
            acc[j].z = fmaf(acc[j].z, al, wt * x[j].z);
            acc[j].w = fmaf(acc[j].w, al, wt * x[j].w);
        }
        m = mn;
#pragma unroll
        for (int j = 0; j < 4; ++j) { x[j] = y[j]; y[j] = z[j]; }
    }

    // ---- combine 4 waves within block ----
    __shared__ float sm[4], sl[4];
    __shared__ float sacc[4][H];          // 16 KB
    if (lane == 0) { sm[w] = m; sl[w] = lsum; }
    __syncthreads();
    const float mp = fmaxf(fmaxf(sm[0], sm[1]), fmaxf(sm[2], sm[3]));
    const float alw = __expf(m - mp);
    float4* sa = (float4*)&sacc[w][0];
#pragma unroll
    for (int j = 0; j < 4; ++j) {
        float4 v;
        v.x = acc[j].x * alw; v.y = acc[j].y * alw;
        v.z = acc[j].z * alw; v.w = acc[j].w * alw;
        sa[lane + 64 * j] = v;
    }
    __syncthreads();
    float lp = 0.f;
#pragma unroll
    for (int ww = 0; ww < 4; ++ww) lp += sl[ww] * __expf(sm[ww] - mp);

    float* dst = ctx_p + (((size_t)b * NC + c) << 10);
#pragma unroll
    for (int i = 0; i < 4; ++i) {
        int h = tid + 256 * i;
        dst[h] = sacc[0][h] + sacc[1][h] + sacc[2][h] + sacc[3][h];
    }
    if (tid == 0) { m_p[b * NC + c] = mp; l_p[b * NC + c] = lp; }
}

// ---------------- k45: fused chunk-combine + pre-slice + matmul + atomic -----
__global__ __launch_bounds__(256) void k45_matmul(
    const float* __restrict__ ctx_p, const float* __restrict__ m_p,
    const float* __restrict__ l_p, const float* __restrict__ h_t,
    const float* __restrict__ Wv, float* __restrict__ accum)
{
    const int kc = blockIdx.x;   // 0..7 (k-chunk of 256)
    const int b  = blockIdx.y;
    const int o  = threadIdx.x;

    __shared__ float sp[256];
    if (kc < 4) {
        float M = -INFINITY;
#pragma unroll
        for (int c = 0; c < NC; ++c) M = fmaxf(M, m_p[b * NC + c]);
        float L = 0.f;
#pragma unroll
        for (int c = 0; c < NC; ++c) L += l_p[b * NC + c] * __expf(m_p[b * NC + c] - M);
        float s = 0.f;
#pragma unroll
        for (int c = 0; c < NC; ++c)
            s += ctx_p[(((size_t)b * NC + c) << 10) + kc * 256 + o]
                 * __expf(m_p[b * NC + c] - M);
        sp[o] = s / L;
    } else {
        sp[o] = h_t[((size_t)b << 10) + (kc - 4) * 256 + o];
    }
    __syncthreads();

    float acc = 0.f;
    const float* wv = Wv + (size_t)kc * 256 * OUTD + o;
#pragma unroll 8
    for (int k = 0; k < 256; ++k)
        acc = fmaf(sp[k], wv[(size_t)k * OUTD], acc);
    atomicAdd(&accum[b * OUTD + o], acc);
}

// ---------------- k5b: out = tanh(accum + bv) --------------------------------
__global__ __launch_bounds__(256) void k5b_tanh(
    const float* __restrict__ accum, const float* __restrict__ bv,
    float* __restrict__ out)
{
    int i = blockIdx.x * 256 + threadIdx.x;
    out[i] = tanhf(accum[i] + bv[i & (OUTD - 1)]);
}

extern "C" void kernel_launch(void* const* d_in, const int* in_sizes, int n_in,
                              void* d_out, int out_size, void* d_ws, size_t ws_size,
                              hipStream_t stream)
{
    const float* hs = (const float*)d_in[0];
    const float* W1 = (const float*)d_in[1];
    const float* b1 = (const float*)d_in[2];
    const float* Wv = (const float*)d_in[3];
    const float* bv = (const float*)d_in[4];
    float* out = (float*)d_out;
    float* ws  = (float*)d_ws;

    float* ph    = ws;                              // KC1*B*H  = 1048576 floats
    float* h_t   = ph + (size_t)KC1 * B * H;        // B*H      = 32768
    float* u     = h_t + (size_t)B * H;             // B*H      = 32768
    float* m_p   = u + (size_t)B * H;               // B*NC     = 1024
    float* l_p   = m_p + B * NC;                    // B*NC     = 1024
    float* ctx_p = l_p + B * NC;                    // B*NC*H   = 1048576
    float* accum = ctx_p + (size_t)B * NC * H;      // B*OUTD   = 8192
    // total ~8.7 MB of d_ws

    k1a_partial_ht<<<dim3(4, KC1), 256, 0, stream>>>(hs, W1, ph);
    k1b_reduce_ht<<<(B * H) / 256, 256, 0, stream>>>(ph, b1, h_t, accum);
    k2_compute_u<<<H / 4, 256, 0, stream>>>(W1, h_t, u);
    k3_fused<<<dim3(NC, B), 256, 0, stream>>>(hs, u, ctx_p, m_p, l_p);
    k45_matmul<<<dim3(8, B), 256, 0, stream>>>(ctx_p, m_p, l_p, h_t, Wv, accum);
    k5b_tanh<<<B, 256, 0, stream>>>(accum, bv, out);
}